// Round 20
// baseline (115.731 us; speedup 1.0000x reference)
//
#include <hip/hip_runtime.h>
#include <hip/hip_bf16.h>

#define TEMP_INV (1.0f / 0.07f)
#define LOG2E 1.4426950408889634f
#define LN2 0.6931471805599453f
#define CFIX 21.0f

typedef __attribute__((ext_vector_type(4))) float f32x4;

__device__ __forceinline__ void gload16(const unsigned char* g,
                                        unsigned char* l) {
  __builtin_amdgcn_global_load_lds(
      (const __attribute__((address_space(1))) void*)g,
      (__attribute__((address_space(3))) void*)l, 16, 0, 0);
}

// ---------------- Kernel 1: L2-normalize -> fp8(e4m3) feats x16, cross, ------
// ---------------- and zero lsum (folded). Verbatim R12/R19 (proven). ---------
__global__ __launch_bounds__(256) void norm_kernel(
    const float* __restrict__ A, const float* __restrict__ P,
    unsigned char* __restrict__ F, float* __restrict__ cross,
    float* __restrict__ lsum, int B, int D) {
  const int row = blockIdx.x;
  const int t = threadIdx.x;
  {
    const int zi = row * 256 + t;
    if (zi < 2 * B) lsum[zi] = 0.f;
  }
  const float4* a4 = reinterpret_cast<const float4*>(A + (size_t)row * D);
  const float4* p4 = reinterpret_cast<const float4*>(P + (size_t)row * D);
  const int n4 = D >> 2;
  float sa = 0.f, sp = 0.f, sx = 0.f;
  for (int i = t; i < n4; i += 256) {
    float4 av = a4[i], pv = p4[i];
    sa += av.x * av.x + av.y * av.y + av.z * av.z + av.w * av.w;
    sp += pv.x * pv.x + pv.y * pv.y + pv.z * pv.z + pv.w * pv.w;
    sx += av.x * pv.x + av.y * pv.y + av.z * pv.z + av.w * pv.w;
  }
#pragma unroll
  for (int off = 32; off; off >>= 1) {
    sa += __shfl_down(sa, off);
    sp += __shfl_down(sp, off);
    sx += __shfl_down(sx, off);
  }
  __shared__ float red[3][4];
  const int wid = t >> 6, lane = t & 63;
  if (lane == 0) { red[0][wid] = sa; red[1][wid] = sp; red[2][wid] = sx; }
  __syncthreads();
  sa = red[0][0] + red[0][1] + red[0][2] + red[0][3];
  sp = red[1][0] + red[1][1] + red[1][2] + red[1][3];
  sx = red[2][0] + red[2][1] + red[2][2] + red[2][3];
  const float ian = rsqrtf(sa), ipn = rsqrtf(sp);
  const float ia = ian * 16.f, ip = ipn * 16.f;  // x16 -> e4m3 range
  unsigned char* fa = F + (size_t)row * D;
  unsigned char* fp = F + (size_t)(B + row) * D;
  for (int i = t; i < n4; i += 256) {
    float4 av = a4[i], pv = p4[i];
    int qa = 0, qp = 0;
    qa = __builtin_amdgcn_cvt_pk_fp8_f32(av.x * ia, av.y * ia, qa, false);
    qa = __builtin_amdgcn_cvt_pk_fp8_f32(av.z * ia, av.w * ia, qa, true);
    qp = __builtin_amdgcn_cvt_pk_fp8_f32(pv.x * ip, pv.y * ip, qp, false);
    qp = __builtin_amdgcn_cvt_pk_fp8_f32(pv.z * ip, pv.w * ip, qp, true);
    reinterpret_cast<int*>(fa)[i] = qa;
    reinterpret_cast<int*>(fp)[i] = qp;
  }
  if (t == 0) cross[row] = sx * ian * ipn;
}

// ---------------- Kernel 2: triangular fused Gram (fp8, 4-deep pipeline) -----
// R12 configuration (measured best; reproduced twice at 115.4/115.35 total)
// + ONE change: iters 13-15's dummy stages now prefetch the NEXT tile's
// regions 0-2 (same buffers: (16..18)&3 = 0,1,2; same issue order as the
// prologue), so tiles 1,2 skip the serial 12-load prologue fill and the
// epilogue's exp2/atomics overlap the prefetch flight. Correctness rests on
// the UNCHANGED inter-tile vmcnt(0)+barrier: all prefetched data is in LDS
// before the next tile's first read; its early vmcnt(8)s pass trivially
// (upper-bound waits). Last tile uses current-tile pointers as harmless
// dummies (R12 tail behavior).
// fp8 region (256 trows x 32 k = 8KB): lrow=trow>>2 (128B bank period);
// cu=(trow&3)*2+(k>=16); chunk=cu^(lrow&7); byte=lrow*128+chunk*16+(k&15).
// Note: the 4-way b64 read aliasing is at the 512B/4-pass throughput floor
// (not a real cost) — verified by arithmetic R19.
#define VT 16  /* K-64 tiles: D/64 */

__global__ __launch_bounds__(512, 2) void gram_lse_kernel(
    const unsigned char* __restrict__ F, float* __restrict__ lsum, int NN,
    int D) {
  __shared__ unsigned char lds8[4][2][2][8192];  // [buf][A/B][khalf][8KB]
  const int nrb = NN >> 8;
  const int ntri = nrb * (nrb + 1) / 2;
  int b = blockIdx.x;
  b = (b & 7) * (gridDim.x >> 3) + (b >> 3);  // XCD swizzle (176 = 8*22)
  const int lin0 = b * 3;

  const int t = threadIdx.x;
  const int lane = t & 63, w = t >> 6;
  const int lo = lane & 15, hi = lane >> 4;
  const int wr = w >> 2, wn = w & 3;  // wr: j-half(128), wn: i-quarter(64)

  // staging decode: chunk c = tid; lrow=c>>3; cu=(c&7)^(lrow&7);
  // trow=lrow*4+(cu>>1); kc=(cu&1)*16
  const int ci = t;
  const int lrS = ci >> 3, cuS = (ci & 7) ^ (lrS & 7);
  const int trowS = lrS * 4 + (cuS >> 1), kcS = (cuS & 1) << 4;
  const int dstW = w * 1024;  // wave-uniform byte base in 8KB region

  // fragment read byte offsets (region-relative, tile-independent)
  int offA[8], offB[4];
#pragma unroll
  for (int mf = 0; mf < 8; ++mf) {
    const int r = wr * 128 + mf * 16 + lo;
    const int lr = r >> 2;
    const int cu = ((r & 3) << 1) | (hi >> 1);
    offA[mf] = lr * 128 + ((cu ^ (lr & 7)) << 4) + ((hi & 1) << 3);
  }
#pragma unroll
  for (int nf = 0; nf < 4; ++nf) {
    const int r = wn * 64 + nf * 16 + lo;
    const int lr = r >> 2;
    const int cu = ((r & 3) << 1) | (hi >> 1);
    offB[nf] = lr * 128 + ((cu ^ (lr & 7)) << 4) + ((hi & 1) << 3);
  }

  const float scl = LOG2E * TEMP_INV / 256.f;  // descale x16*x16

  for (int ti = 0; ti < 3; ++ti) {
    const int lin = lin0 + ti;
    int by = (int)((sqrtf(8.f * (float)lin + 1.f) - 1.f) * 0.5f);
    while ((by + 1) * (by + 2) / 2 <= lin) ++by;
    while (by * (by + 1) / 2 > lin) --by;
    const int bx = lin - by * (by + 1) / 2;  // bx <= by
    const int r0 = bx * 256;  // i rows (B operand, N side)
    const int c0 = by * 256;  // j rows (A operand, M side)
    const bool diag = (bx == by);

    const unsigned char* srcA = F + (size_t)(c0 + trowS) * D + kcS;
    const unsigned char* srcB = F + (size_t)(r0 + trowS) * D + kcS;

    // next tile this block will run (for cross-tile prefetch); last tile:
    // dummy = current (harmless re-stage, drained by inter-tile vmcnt(0))
    const int linN = (ti < 2) ? (lin + 1) : lin;
    int byN = (int)((sqrtf(8.f * (float)linN + 1.f) - 1.f) * 0.5f);
    while ((byN + 1) * (byN + 2) / 2 <= linN) ++byN;
    while (byN * (byN + 1) / 2 > linN) --byN;
    const int bxN = linN - byN * (byN + 1) / 2;
    const unsigned char* srcA2 = F + (size_t)(byN * 256 + trowS) * D + kcS;
    const unsigned char* srcB2 = F + (size_t)(bxN * 256 + trowS) * D + kcS;

#define STAGE_A(T, KS)                                                    \
  do {                                                                    \
    const unsigned char* pa_ =                                            \
        ((T) < VT) ? (srcA + (T) * 64) : (srcA2 + ((T) - VT) * 64);       \
    gload16(pa_ + (KS) * 32, &lds8[(T) & 3][0][KS][dstW]);                \
  } while (0)
#define STAGE_B(T, KS)                                                    \
  do {                                                                    \
    const unsigned char* pb_ =                                            \
        ((T) < VT) ? (srcB + (T) * 64) : (srcB2 + ((T) - VT) * 64);       \
    gload16(pb_ + (KS) * 32, &lds8[(T) & 3][1][KS][dstW]);                \
  } while (0)

    f32x4 acc[8][4];
#pragma unroll
    for (int a = 0; a < 8; ++a)
#pragma unroll
      for (int bb = 0; bb < 4; ++bb) acc[a][bb] = (f32x4){0.f, 0.f, 0.f, 0.f};

    if (ti == 0) {
      // first tile only: serial prologue (tiles 0,1,2 -> 12 loads in flight).
      // For ti>0 these regions were prefetched by the previous tile's
      // iters 13-15 and are already in LDS (inter-tile vmcnt(0) drained).
#pragma unroll
      for (int pt = 0; pt < 3; ++pt) {
        STAGE_A(pt, 0); STAGE_B(pt, 0);
        STAGE_A(pt, 1); STAGE_B(pt, 1);
      }
    }

    for (int v = 0; v < VT; ++v) {
      const int buf = v & 3;
      // steady state: tiles v+1, v+2 stay in flight (8 loads); tile v drained.
      // Early iters of ti>0: fewer in flight -> passes trivially (data in LDS).
      asm volatile("s_waitcnt vmcnt(8)" ::: "memory");
      __builtin_amdgcn_s_barrier();
      asm volatile("" ::: "memory");

#pragma unroll
      for (int KS = 0; KS < 2; ++KS) {
        const unsigned char* RA = &lds8[buf][0][KS][0];
        const unsigned char* RB = &lds8[buf][1][KS][0];
        long aF[8], bF[4];
#pragma unroll
        for (int nf = 0; nf < 4; ++nf) bF[nf] = *(const long*)(RB + offB[nf]);
#pragma unroll
        for (int mf = 0; mf < 8; ++mf) aF[mf] = *(const long*)(RA + offA[mf]);

        if (KS == 0) { STAGE_A(v + 3, 0); STAGE_B(v + 3, 0); }
        else         { STAGE_A(v + 3, 1); STAGE_B(v + 3, 1); }

        __builtin_amdgcn_s_setprio(1);
#pragma unroll
        for (int mf = 0; mf < 8; ++mf)
#pragma unroll
          for (int nf = 0; nf < 4; ++nf)
            acc[mf][nf] = __builtin_amdgcn_mfma_f32_16x16x32_fp8_fp8(
                aF[mf], bF[nf], acc[mf][nf], 0, 0, 0);
        __builtin_amdgcn_s_setprio(0);
      }
      asm volatile("" ::: "memory");
    }

    // ---- dual-side epilogue (verbatim mapping, absmax-0 verified R6-R19) ----
    // acc[mf][nf][rg]: j = c0 + wr*128 + mf*16 + hi*4 + rg
    //                  i = r0 + wn*64 + nf*16 + lo
    // Overlaps the in-flight next-tile prefetch (no vm waits until below).
    float s_i[4] = {0.f, 0.f, 0.f, 0.f};
    float s_j[32];
#pragma unroll
    for (int q = 0; q < 32; ++q) s_j[q] = 0.f;
    {
      const int jb2 = c0 + wr * 128;
#pragma unroll
      for (int nf = 0; nf < 4; ++nf) {
        const int dg = (r0 + wn * 64 + nf * 16 + lo) - jb2;
#pragma unroll
        for (int mf = 0; mf < 8; ++mf)
#pragma unroll
          for (int rg = 0; rg < 4; ++rg) {
            const int jloc = mf * 16 + hi * 4 + rg;
            float e = exp2f(acc[mf][nf][rg] * scl - CFIX);
            if (diag && dg == jloc) e = 0.f;
            s_i[nf] += e;
            s_j[mf * 4 + rg] += e;
          }
      }
    }
#pragma unroll
    for (int nf = 0; nf < 4; ++nf) {
      float v = s_i[nf];
      v += __shfl_xor(v, 16);
      v += __shfl_xor(v, 32);
      if (hi == 0) atomicAdd(&lsum[r0 + wn * 64 + nf * 16 + lo], v);
    }
    if (!diag) {
#pragma unroll
      for (int q = 0; q < 32; ++q) {
        float v = s_j[q];
        v += __shfl_xor(v, 1);
        v += __shfl_xor(v, 2);
        v += __shfl_xor(v, 4);
        v += __shfl_xor(v, 8);
        if (lo == 0)
          atomicAdd(&lsum[c0 + wr * 128 + (q >> 2) * 16 + hi * 4 + (q & 3)],
                    v);
      }
    }

    // inter-tile drain (UNCHANGED safety net): prefetched next-tile stages +
    // atomics all land; next tile's reads of bufs 0-2 are then LDS-valid and
    // buf reuse is WAR-safe.
    asm volatile("s_waitcnt vmcnt(0)" ::: "memory");
    __builtin_amdgcn_s_barrier();
    asm volatile("" ::: "memory");
#undef STAGE_A
#undef STAGE_B
  }
}

// ---------------- Kernel 3: merged finalize (single block) -------------------
__global__ __launch_bounds__(1024) void finalize_kernel(
    const float* __restrict__ lsum, const float* __restrict__ cross,
    const int* __restrict__ labels, float* __restrict__ out, int B) {
  const int NN = 2 * B;
  const int t = threadIdx.x;
  float sum = 0.f, cnt = 0.f;
  for (int i = t; i < NN; i += 1024) {
    const float lse = LN2 * (CFIX + log2f(lsum[i]));
    const float lab = (float)labels[i % B];
    sum += (lse - cross[i % B] * TEMP_INV) * lab;
    cnt += lab;
  }
#pragma unroll
  for (int off = 32; off; off >>= 1) {
    sum += __shfl_down(sum, off);
    cnt += __shfl_down(cnt, off);
  }
  __shared__ float rs[16], rc[16];
  const int wid = t >> 6, lane = t & 63;
  if (lane == 0) { rs[wid] = sum; rc[wid] = cnt; }
  __syncthreads();
  if (t == 0) {
    float S = 0.f, C = 0.f;
    for (int q = 0; q < 16; ++q) { S += rs[q]; C += rc[q]; }
    out[0] = (C > 0.f) ? S / C : 0.f;
  }
}

extern "C" void kernel_launch(void* const* d_in, const int* in_sizes, int n_in,
                              void* d_out, int out_size, void* d_ws, size_t ws_size,
                              hipStream_t stream) {
  const float* A = (const float*)d_in[0];
  const float* P = (const float*)d_in[1];
  const int* labels = (const int*)d_in[2];
  float* out = (float*)d_out;
  const int B = in_sizes[2];
  const int D = in_sizes[0] / B;
  const int NN = 2 * B;

  char* ws = (char*)d_ws;
  unsigned char* F = (unsigned char*)ws;
  size_t off = (size_t)NN * D;  // fp8: 1 B/elem
  off = (off + 255) & ~(size_t)255;
  float* cross = (float*)(ws + off);
  off += (size_t)B * sizeof(float);
  off = (off + 255) & ~(size_t)255;
  float* lsum = (float*)(ws + off);

  norm_kernel<<<B, 256, 0, stream>>>(A, P, F, cross, lsum, B, D);
  const int nrb = NN >> 8;               // 32 row-panels of 256
  const int ntri = nrb * (nrb + 1) / 2;  // 528 = 176 * 3 exactly
  gram_lse_kernel<<<ntri / 3, 512, 0, stream>>>(F, lsum, NN, D);
  finalize_kernel<<<1, 1024, 0, stream>>>(lsum, cross, labels, out, B);
}